// Round 15
// baseline (469.460 us; speedup 1.0000x reference)
//
#include <hip/hip_runtime.h>
#include <hip/hip_bf16.h>

#define NNODE 50000
#define NEDGE 250000

typedef __hip_bfloat16 bf16;
typedef __attribute__((ext_vector_type(8))) short short8v;
typedef __attribute__((ext_vector_type(4))) float f32x4;

__device__ __forceinline__ float b2f(bf16 x){ return __bfloat162float(x); }
__device__ __forceinline__ bf16  f2b(float x){ return __float2bfloat16(x); }
__device__ __forceinline__ short f2s(float x){ bf16 h=f2b(x); short s; __builtin_memcpy(&s,&h,2); return s; }
__device__ __forceinline__ float s2f(short s){ bf16 h; __builtin_memcpy(&h,&s,2); return b2f(h); }
__device__ __forceinline__ float sigm(float x){ return 1.0f/(1.0f+__expf(-x)); }
__device__ __forceinline__ float wred64(float v){
  #pragma unroll
  for(int o=32;o>0;o>>=1) v+=__shfl_xor(v,o,64);
  return v;
}
__device__ __forceinline__ float gred16(float v){
  v+=__shfl_xor(v,1,64); v+=__shfl_xor(v,2,64); v+=__shfl_xor(v,4,64); v+=__shfl_xor(v,8,64);
  return v;
}
__device__ __forceinline__ int ired64(int v){
  #pragma unroll
  for(int o=32;o>0;o>>=1) v+=__shfl_xor(v,o,64);
  return v;
}
// byte offset of element (row r, k) inside a multi-kt A-frag region (kt stride 1024B)
__device__ __forceinline__ int fragOff(int r, int k){
  int kt=k>>5, k32=k&31, half=k32>>4, g=(k32&15)>>2, j=k32&3;
  return (kt<<10)+((r+(g<<4))<<4)+(half<<3)+(j<<1);
}
__device__ __forceinline__ short8v pack8(float4 a, float4 b){
  short8v s; s[0]=f2s(a.x);s[1]=f2s(a.y);s[2]=f2s(a.z);s[3]=f2s(a.w);
  s[4]=f2s(b.x);s[5]=f2s(b.y);s[6]=f2s(b.z);s[7]=f2s(b.w); return s;
}
__device__ __forceinline__ short8v pack8s(short4 a, short4 b){
  short8v s; s[0]=a.x;s[1]=a.y;s[2]=a.z;s[3]=a.w;s[4]=b.x;s[5]=b.y;s[6]=b.z;s[7]=b.w; return s;
}

// ---------------------------------------------------------------------------
// Weight-prep tile map (each tile 1KB: 64 lanes x 8 bf16)
// ---------------------------------------------------------------------------
#define T_WOS 0
#define T_WOV 32
#define T_W1S 40
#define T_W1V 88
#define T_W2S 96
#define T_W2V 128
#define T_WE  136
#define T_WQ  168
#define T_WK  232
#define T_WVS 296
#define T_WSS 328
#define T_WSSG 360
#define T_WSV 376
#define T_WVV 392
#define T_WVVS 400
#define T_WVVG 416
#define T_WVS2 424
#define T_WVVV 432
#define T_TOT 440

__global__ __launch_bounds__(64) void k_prep(
  const float* __restrict__ Wo_s, const float* __restrict__ Wo_v,
  const float* __restrict__ W1_s, const float* __restrict__ W1_v,
  const float* __restrict__ W2_s, const float* __restrict__ W2_v,
  const float* __restrict__ WeM,
  const float* __restrict__ Wq, const float* __restrict__ Wk,
  const float* __restrict__ Wv_s,
  const float* __restrict__ w_ss, const float* __restrict__ w_ssg,
  const float* __restrict__ w_sv,
  const float* __restrict__ Wv_v, const float* __restrict__ w_vv_s,
  const float* __restrict__ w_vvg, const float* __restrict__ w_vs,
  const float* __restrict__ w_vvv,
  short* __restrict__ P)
{
  const int T=blockIdx.x, l=threadIdx.x;
  const float* W; int N, KT, lt;
  if(T<T_WOV){ W=Wo_s; N=128; KT=4; lt=T; }
  else if(T<T_W1S){ W=Wo_v; N=64; KT=2; lt=T-T_WOV; }
  else if(T<T_W1V){ W=W1_s; N=192; KT=4; lt=T-T_W1S; }
  else if(T<T_W2S){ W=W1_v; N=64; KT=2; lt=T-T_W1V; }
  else if(T<T_W2V){ W=W2_s; N=128; KT=4; lt=T-T_W2S; }
  else if(T<T_WE){ W=W2_v; N=64; KT=2; lt=T-T_W2V; }
  else if(T<T_WQ){ W=WeM; N=256; KT=2; lt=T-T_WE; }
  else if(T<T_WK){ W=Wq; N=256; KT=4; lt=T-T_WQ; }
  else if(T<T_WVS){ W=Wk; N=256; KT=4; lt=T-T_WK; }
  else if(T<T_WSS){ W=Wv_s; N=128; KT=4; lt=T-T_WVS; }
  else if(T<T_WSSG){ W=w_ss; N=128; KT=4; lt=T-T_WSS; }
  else if(T<T_WSV){ W=w_ssg; N=64; KT=4; lt=T-T_WSSG; }
  else if(T<T_WVV){ W=w_sv; N=64; KT=4; lt=T-T_WSV; }
  else if(T<T_WVVS){ W=Wv_v; N=64; KT=2; lt=T-T_WVV; }
  else if(T<T_WVVG){ W=w_vv_s; N=128; KT=2; lt=T-T_WVVS; }
  else if(T<T_WVS2){ W=w_vvg; N=64; KT=2; lt=T-T_WVVG; }
  else if(T<T_WVVV){ W=w_vs; N=64; KT=2; lt=T-T_WVS2; }
  else { W=w_vvv; N=64; KT=2; lt=T-T_WVVV; }
  const int nt=lt/KT, kt=lt-nt*KT;
  const int col=nt*16+(l&15);
  short8v o;
  #pragma unroll
  for(int j=0;j<8;j++){
    int k=kt*32+((j>>2)<<4)+((l>>4)<<2)+(j&3);
    o[j]=f2s(W[(size_t)k*N+col]);
  }
  *(short8v*)(P+((size_t)T<<9)+(l<<3))=o;
}

// ---------------------------------------------------------------------------
// K1 (MFMA): Q,K (bf16) and NREC g0 = {S1(128), S2(64), sv(64)}
// ---------------------------------------------------------------------------
__global__ __launch_bounds__(256) void k1_mfma(
  const float* __restrict__ nf, const short* __restrict__ P,
  const float* __restrict__ bq, const float* __restrict__ bk,
  const float* __restrict__ bvs,
  bf16* __restrict__ Q, bf16* __restrict__ K, short* __restrict__ NREC2)
{
  __shared__ __align__(16) short nsF[4*512];
  __shared__ __align__(16) short vsF[4*512];
  const int t=threadIdx.x, l=t&63, w=t>>6;
  const int n0=blockIdx.x*16;
  for(int i=t;i<512;i+=256){
    int r=i>>5, c=(i&31)<<2;
    const float4 v=*(const float4*)&nf[(size_t)(n0+r)*320+c];
    short4 s; s.x=f2s(v.x); s.y=f2s(v.y); s.z=f2s(v.z); s.w=f2s(v.w);
    *(short4*)((char*)nsF+fragOff(r,c))=s;
  }
  __syncthreads();
  short8v a[4];
  #pragma unroll
  for(int kt=0;kt<4;kt++) a[kt]=*(const short8v*)((const char*)nsF+(kt<<10)+(l<<4));
  #pragma unroll
  for(int ii=0;ii<4;ii++){
    int nt=w+(ii<<2);
    f32x4 accq={0.f,0.f,0.f,0.f}, acck={0.f,0.f,0.f,0.f};
    #pragma unroll
    for(int kt=0;kt<4;kt++){
      short8v bq8=*(const short8v*)(P+(((size_t)(T_WQ+nt*4+kt))<<9)+(l<<3));
      short8v bk8=*(const short8v*)(P+(((size_t)(T_WK+nt*4+kt))<<9)+(l<<3));
      accq=__builtin_amdgcn_mfma_f32_16x16x32_bf16(a[kt],bq8,accq,0,0,0);
      acck=__builtin_amdgcn_mfma_f32_16x16x32_bf16(a[kt],bk8,acck,0,0,0);
    }
    int col=(nt<<4)+(l&15);
    float bqs=bq[col], bks=bk[col];
    #pragma unroll
    for(int r=0;r<4;r++){
      int row=((l>>4)<<2)+r;
      Q[(size_t)(n0+row)*256+col]=f2b(accq[r]+bqs);
      K[(size_t)(n0+row)*256+col]=f2b(acck[r]+bks);
    }
  }
  #pragma unroll
  for(int ii=0;ii<2;ii++){
    int nt=w+(ii<<2);
    f32x4 acc={0.f,0.f,0.f,0.f};
    #pragma unroll
    for(int kt=0;kt<4;kt++){
      short8v b=*(const short8v*)(P+(((size_t)(T_WVS+nt*4+kt))<<9)+(l<<3));
      acc=__builtin_amdgcn_mfma_f32_16x16x32_bf16(a[kt],b,acc,0,0,0);
    }
    int col=(nt<<4)+(l&15);
    float bv=bvs[col];
    #pragma unroll
    for(int r=0;r<4;r++){
      int row=((l>>4)<<2)+r;
      *(short*)((char*)vsF+fragOff(row,col))=f2s(acc[r]+bv);
    }
  }
  __syncthreads();
  #pragma unroll
  for(int kt=0;kt<4;kt++) a[kt]=*(const short8v*)((const char*)vsF+(kt<<10)+(l<<4));
  #pragma unroll
  for(int ii=0;ii<4;ii++){
    int nt=w+(ii<<2);
    int bt;
    if(nt<8) bt=T_WSS+nt*4;
    else if(nt<12) bt=T_WSSG+(nt-8)*4;
    else bt=T_WSV+(nt-12)*4;
    f32x4 acc={0.f,0.f,0.f,0.f};
    #pragma unroll
    for(int kt=0;kt<4;kt++){
      short8v b=*(const short8v*)(P+(((size_t)(bt+kt))<<9)+(l<<3));
      acc=__builtin_amdgcn_mfma_f32_16x16x32_bf16(a[kt],b,acc,0,0,0);
    }
    int col=(nt<<4)+(l&15);
    int lane, sslot;
    if(nt<8){ lane=col&63; sslot=(col>=64)?1:0; }
    else if(nt<12){ lane=col-128; sslot=2; }
    else { lane=col-192; sslot=3; }
    #pragma unroll
    for(int r=0;r<4;r++){
      int row=((l>>4)<<2)+r;
      NREC2[(size_t)(n0+row)*1280 + (lane<<2) + sslot]=f2s(acc[r]);
    }
  }
}

// ---------------------------------------------------------------------------
// K2 (MFMA): NREC groups g1..g4 = {D1(3x128), D2(3x64), Wvs(3x64), Cn(3x64)}
// ---------------------------------------------------------------------------
__global__ __launch_bounds__(256) void k2_mfma(
  const float* __restrict__ nf, const short* __restrict__ P,
  short* __restrict__ NREC2)
{
  __shared__ __align__(16) short nvF[6*512];
  __shared__ __align__(16) short vvF[6*512];
  const int t=threadIdx.x, l=t&63, w=t>>6;
  const int n0=blockIdx.x*16;
  for(int i=t;i<3072;i+=256){
    int r=i/192, c=i-r*192;
    int v=c/3, k=c-3*v;
    float x=nf[(size_t)(n0+r)*320+128+c];
    *(short*)((char*)nvF+(k<<11)+fragOff(r,v))=f2s(x);
  }
  __syncthreads();
  #pragma unroll
  for(int jj=0;jj<3;jj++){
    int job=w+(jj<<2);
    int p=job>>2, nt=job&3;
    f32x4 acc={0.f,0.f,0.f,0.f};
    #pragma unroll
    for(int kt=0;kt<2;kt++){
      short8v a2=*(const short8v*)((const char*)nvF+(p<<11)+(kt<<10)+(l<<4));
      short8v b=*(const short8v*)(P+(((size_t)(T_WVV+nt*2+kt))<<9)+(l<<3));
      acc=__builtin_amdgcn_mfma_f32_16x16x32_bf16(a2,b,acc,0,0,0);
    }
    int col=(nt<<4)+(l&15);
    #pragma unroll
    for(int r=0;r<4;r++){
      int row=((l>>4)<<2)+r;
      *(short*)((char*)vvF+(p<<11)+fragOff(row,col))=f2s(acc[r]);
    }
  }
  __syncthreads();
  #pragma unroll
  for(int jj=0;jj<15;jj++){
    int job=w+(jj<<2);
    int p=job/20, r20=job-p*20;
    int nt, bt, G0;
    if(r20<8){ nt=r20; bt=T_WVVS+nt*2; G0=0; }
    else if(r20<12){ nt=r20-8; bt=T_WVVG+nt*2; G0=1; }
    else if(r20<16){ nt=r20-12; bt=T_WVS2+nt*2; G0=2; }
    else { nt=r20-16; bt=T_WVVV+nt*2; G0=3; }
    f32x4 acc={0.f,0.f,0.f,0.f};
    #pragma unroll
    for(int kt=0;kt<2;kt++){
      short8v a2=*(const short8v*)((const char*)vvF+(p<<11)+(kt<<10)+(l<<4));
      short8v b=*(const short8v*)(P+(((size_t)(bt+kt))<<9)+(l<<3));
      acc=__builtin_amdgcn_mfma_f32_16x16x32_bf16(a2,b,acc,0,0,0);
    }
    int col=(nt<<4)+(l&15);
    int G;
    if(G0==0)      G = p*2 + (col>=64 ? 1 : 0);
    else if(G0==1) G = 6 + p;
    else if(G0==2) G = 9 + p;
    else           G = 12 + p;
    int lane = col & 63;
    int addr = ((1+(G>>2))<<8) + (lane<<2) + (G&3);
    #pragma unroll
    for(int r=0;r<4;r++){
      int row=((l>>4)<<2)+r;
      NREC2[(size_t)(n0+row)*1280 + addr]=f2s(acc[r]);
    }
  }
}

// ---------------------------------------------------------------------------
// Sort-by-dst: histogram -> 3-kernel scan -> scatter (index + payload).
// ---------------------------------------------------------------------------
__global__ __launch_bounds__(256) void k_hist(const int* __restrict__ eidx, int* __restrict__ counts){
  int e=blockIdx.x*256+threadIdx.x;
  if(e<NEDGE) atomicAdd(&counts[eidx[NEDGE+e]],1);
}

#define SCAN_NB 196

__global__ __launch_bounds__(256) void k_scan1(const int* __restrict__ counts, int* __restrict__ bsum){
  const int t=threadIdx.x, ln=t&63, wid=t>>6;
  int idx=blockIdx.x*256+t;
  int v=(idx<NNODE)?counts[idx]:0;
  int s=ired64(v);
  __shared__ int ws[4];
  if(ln==0) ws[wid]=s;
  __syncthreads();
  if(t==0) bsum[blockIdx.x]=ws[0]+ws[1]+ws[2]+ws[3];
}

__global__ __launch_bounds__(256) void k_scan2(const int* __restrict__ bsum, int* __restrict__ boff){
  const int t=threadIdx.x, ln=t&63, wid=t>>6;
  int v=(t<SCAN_NB)?bsum[t]:0;
  int incl=v;
  #pragma unroll
  for(int o=1;o<64;o<<=1){ int x=__shfl_up(incl,o,64); if(ln>=o) incl+=x; }
  __shared__ int wtot[4], wpre[4];
  if(ln==63) wtot[wid]=incl;
  __syncthreads();
  if(t==0){ int s=0; for(int k=0;k<4;k++){ wpre[k]=s; s+=wtot[k]; } }
  __syncthreads();
  if(t<SCAN_NB) boff[t]=wpre[wid]+incl-v;
}

__global__ __launch_bounds__(256) void k_scan3(const int* __restrict__ counts, const int* __restrict__ boff,
                                               int* __restrict__ off, int* __restrict__ cursor){
  const int t=threadIdx.x, ln=t&63, wid=t>>6;
  int idx=blockIdx.x*256+t;
  int v=(idx<NNODE)?counts[idx]:0;
  int incl=v;
  #pragma unroll
  for(int o=1;o<64;o<<=1){ int x=__shfl_up(incl,o,64); if(ln>=o) incl+=x; }
  __shared__ int wtot[4], wpre[4];
  if(ln==63) wtot[wid]=incl;
  __syncthreads();
  if(t==0){ int s=0; for(int k=0;k<4;k++){ wpre[k]=s; s+=wtot[k]; } }
  __syncthreads();
  int excl=boff[blockIdx.x]+wpre[wid]+incl-v;
  if(idx<NNODE){ off[idx]=excl; cursor[idx]=excl; }
  if(blockIdx.x==SCAN_NB-1 && t==255) off[NNODE]=NEDGE;
}

__global__ __launch_bounds__(256) void k_scatter(
  const int* __restrict__ eidx, const float* __restrict__ esh,
  int* __restrict__ cursor, int* __restrict__ eord,
  int* __restrict__ srcs, int* __restrict__ dsts, float* __restrict__ eshs)
{
  int e=blockIdx.x*256+threadIdx.x;
  if(e<NEDGE){
    int d=eidx[NEDGE+e];
    int pos=atomicAdd(&cursor[d],1);
    eord[pos]=e;
    srcs[pos]=eidx[e];
    dsts[pos]=d;
    *(float4*)&eshs[(size_t)pos*4]=*(const float4*)&esh[(size_t)e*4];
  }
}

// ---------------------------------------------------------------------------
// K3 (MFMA, sorted order): ef = edge_attr@We + be; scores -> SC (sorted).
// ---------------------------------------------------------------------------
__global__ __launch_bounds__(256) void k3_mfma(
  const float* __restrict__ eattr,
  const int* __restrict__ EORD, const int* __restrict__ SRCs, const int* __restrict__ DSTs,
  const short* __restrict__ P, const float* __restrict__ be,
  const bf16* __restrict__ Q, const bf16* __restrict__ K,
  float* __restrict__ SC)
{
  __shared__ __align__(16) short aeF[2*512];
  __shared__ __align__(16) float ef[16][260];
  __shared__ int sed[16], ssrc[16], sdst[16];
  const int t=threadIdx.x, l=t&63, w=t>>6;
  const int e0=blockIdx.x*16;
  if(t<16){
    sed[t]=EORD[e0+t];
    ssrc[t]=SRCs[e0+t];
    sdst[t]=DSTs[e0+t];
  }
  __syncthreads();
  {
    int r=t>>4, c4=(t&15)<<2;
    const float4 v=*(const float4*)&eattr[(size_t)sed[r]*64+c4];
    short4 s; s.x=f2s(v.x); s.y=f2s(v.y); s.z=f2s(v.z); s.w=f2s(v.w);
    *(short4*)((char*)aeF+fragOff(r,c4))=s;
  }
  __syncthreads();
  {
    short8v a0=*(const short8v*)((const char*)aeF+(l<<4));
    short8v a1=*(const short8v*)((const char*)aeF+1024+(l<<4));
    #pragma unroll
    for(int ii=0;ii<4;ii++){
      int nt=w+(ii<<2);
      f32x4 acc={0.f,0.f,0.f,0.f};
      short8v b0=*(const short8v*)(P+(((size_t)(T_WE+nt*2+0))<<9)+(l<<3));
      short8v b1=*(const short8v*)(P+(((size_t)(T_WE+nt*2+1))<<9)+(l<<3));
      acc=__builtin_amdgcn_mfma_f32_16x16x32_bf16(a0,b0,acc,0,0,0);
      acc=__builtin_amdgcn_mfma_f32_16x16x32_bf16(a1,b1,acc,0,0,0);
      int col=(nt<<4)+(l&15);
      float bv=be[col];
      #pragma unroll
      for(int r=0;r<4;r++){ int row=((l>>4)<<2)+r; ef[row][col]=acc[r]+bv; }
    }
  }
  __syncthreads();
  {
    const int h=l&15, qt=l>>4;
    const int ch=h*16+(qt<<2);
    #pragma unroll
    for(int j=0;j<4;j++){
      int el=w*4+j;
      int s=ssrc[el], d=sdst[el];
      short4 qs=*(const short4*)((const short*)Q+(size_t)d*256+ch);
      short4 ks=*(const short4*)((const short*)K+(size_t)s*256+ch);
      const float4 e4=*(const float4*)&ef[el][ch];
      float p = s2f(qs.x)*(s2f(ks.x)+e4.x)
              + s2f(qs.y)*(s2f(ks.y)+e4.y)
              + s2f(qs.z)*(s2f(ks.z)+e4.z)
              + s2f(qs.w)*(s2f(ks.w)+e4.w);
      p += __shfl_xor(p,16,64);
      p += __shfl_xor(p,32,64);
      if(qt==0) SC[(size_t)(e0+el)*16+h]=p*0.25f;
    }
  }
}

// ---------------------------------------------------------------------------
// K5: per-edge attention weight -> ATTs. SC is in sorted order -> streamed.
// ---------------------------------------------------------------------------
__global__ __launch_bounds__(256) void k5_att(
  const float* __restrict__ SC, const int* __restrict__ OFF,
  float* __restrict__ ATTs)
{
  const int l=threadIdx.x&63;
  const int n=blockIdx.x*4+(threadIdx.x>>6);
  const int beg=OFF[n], end=OFF[n+1];
  const int j=l>>4, h=l&15;
  float mh=-1e30f;
  for(int i=beg+j;i<end;i+=4) mh=fmaxf(mh, SC[(size_t)i*16+h]);
  mh=fmaxf(mh,__shfl_xor(mh,16,64));
  mh=fmaxf(mh,__shfl_xor(mh,32,64));
  float dh=0.f;
  for(int i=beg+j;i<end;i+=4) dh+=__expf(SC[(size_t)i*16+h]-mh);
  dh+=__shfl_xor(dh,16,64);
  dh+=__shfl_xor(dh,32,64);
  float rdh=(end>beg)?1.f/dh:0.f;
  for(int i0=beg;i0<end;i0+=4){
    int i=i0+j;
    float a=0.f; bool act=(i<end);
    if(act) a=__expf(SC[(size_t)i*16+h]-mh)*rdh;
    a=gred16(a);
    if(h==0 && act) ATTs[i]=a*(1.f/16.f);
  }
}

// ---------------------------------------------------------------------------
// K6: per-dst-node aggregation. One wave per node, 4 nodes/block.
// Aggregates written as bf16 (AGSh/AGVh).
// ---------------------------------------------------------------------------
__global__ __launch_bounds__(256) void k6_agg(
  const int* __restrict__ SRCs, const float* __restrict__ ESHs,
  const short* __restrict__ NREC2, const float* __restrict__ ATTs,
  const int* __restrict__ OFF,
  const float* __restrict__ b_ms, const float* __restrict__ b_mg,
  short* __restrict__ AGSh, short* __restrict__ AGVh)
{
  const int l = threadIdx.x & 63;
  const int n = blockIdx.x*4 + (threadIdx.x>>6);
  const int beg=OFF[n], end=OFF[n+1];
  const float bmsa=b_ms[l], bmsb=b_ms[64+l], bmgv=b_mg[l];

  float as0=0.f,as1=0.f,av0acc=0.f,av1acc=0.f,av2acc=0.f;
  for(int i=beg;i<end;i++){
    const int s=SRCs[i];
    const float att=ATTs[i];
    const float4 sh4=*(const float4*)&ESHs[(size_t)i*4];
    const float shs=sh4.x, sh0=sh4.y, sh1=sh4.z, sh2=sh4.w;

    const short* R = NREC2 + (size_t)s*1280 + (l<<2);
    const short4 q0=*(const short4*)(R);
    const short4 q1=*(const short4*)(R+256);
    const short4 q2=*(const short4*)(R+512);
    const short4 q3=*(const short4*)(R+768);
    const short4 q4=*(const short4*)(R+1024);

    float msa = shs*s2f(q0.x) + s2f(q1.x)*sh0 + s2f(q1.z)*sh1 + s2f(q2.x)*sh2 + bmsa;
    float msb = shs*s2f(q0.y) + s2f(q1.y)*sh0 + s2f(q1.w)*sh1 + s2f(q2.y)*sh2 + bmsb;
    float mgv = shs*s2f(q0.z) + s2f(q2.z)*sh0 + s2f(q2.w)*sh1 + s2f(q3.x)*sh2 + bmgv;

    float sum = wred64(msa+msb+mgv);
    float sq  = wred64(msa*msa+msb*msb+mgv*mgv);
    float mean = sum*(1.f/192.f);
    float var  = sq*(1.f/192.f) - mean*mean;
    float rs   = rsqrtf(var + 1e-5f);

    const float svv=s2f(q0.w);
    const float w0=s2f(q3.y), w1=s2f(q3.z), w2=s2f(q3.w);
    const float c0=s2f(q4.x), c1=s2f(q4.y), c2=s2f(q4.z);
    float cr0 = c1*sh2 - c2*sh1;
    float cr1 = c2*sh0 - c0*sh2;
    float cr2 = c0*sh1 - c1*sh0;
    float mv0 = svv*sh0 + shs*w0 + cr0;
    float mv1 = svv*sh1 + shs*w1 + cr1;
    float mv2 = svv*sh2 + shs*w2 + cr2;
    float vsq = wred64(mv0*mv0+mv1*mv1+mv2*mv2);
    float vn  = rsqrtf(vsq*(1.f/64.f) + 1e-5f);

    float sga=(msa-mean)*rs, sgb=(msb-mean)*rs, sgg=(mgv-mean)*rs;
    float wV = vn * sigm(sgg) * att;
    as0 += sga*sigm(sga)*att;
    as1 += sgb*sigm(sgb)*att;
    av0acc += mv0*wV;
    av1acc += mv1*wV;
    av2acc += mv2*wV;
  }
  AGSh[(size_t)n*128+l]     =f2s(as0);
  AGSh[(size_t)n*128+64+l]  =f2s(as1);
  AGVh[(size_t)n*192+l]     =f2s(av0acc);
  AGVh[(size_t)n*192+64+l]  =f2s(av1acc);
  AGVh[(size_t)n*192+128+l] =f2s(av2acc);
}

// ---------------------------------------------------------------------------
// K7 (MFMA, v4): final node update. 32 nodes/block, 8 waves (512 thr).
// Row-tile rt=w>>2 selects node half; LDS ~62KB -> 2 blocks/CU.
// ---------------------------------------------------------------------------
#define K7NBLK ((NNODE+31)/32)
__global__ __launch_bounds__(512) void k7_mfma(
  const float* __restrict__ nf,
  const short* __restrict__ AGSh, const short* __restrict__ AGVh,
  const short* __restrict__ P,
  const float* __restrict__ bo_s, const float* __restrict__ b1_s, const float* __restrict__ b2_s,
  float* __restrict__ out)
{
  __shared__ float xs[32][132];
  __shared__ short xvh[32][200];
  __shared__ short ffh[32][204];
  __shared__ __align__(16) short asA[2][4*512];
  __shared__ __align__(16) short avA[2][6*512];
  __shared__ float smean[32], srs[32], svn[32];
  const int t=threadIdx.x, l=t&63, w=t>>6;
  const int rt=w>>2, wq=w&3;
  const int n0=blockIdx.x*32;
  const int seg=t>>6, lam=t&63;
  const int sfr=lam&15, sfg=lam>>4;

  // ---- P0: residuals + frag-stage AGSh/AGVh (bf16, direct short4 copies)
  for(int i=t;i<4096;i+=512){ int r=i>>7,c=i&127; int nd=n0+r; xs[r][c]=(nd<NNODE)?nf[(size_t)nd*320+c]:0.f; }
  for(int i=t;i<6144;i+=512){ int r=i/192,cc=i-r*192; int k=cc>>6,u=cc&63; int nd=n0+r; xvh[r][cc]=(nd<NNODE)?f2s(nf[(size_t)nd*320+128+u*3+k]):(short)0; }
  {
    int srt=seg>>2, skt=seg&3;
    int nd=n0+srt*16+sfr;
    short4 va={0,0,0,0}, vb={0,0,0,0};
    if(nd<NNODE){
      const short* b=AGSh+(size_t)nd*128+skt*32+(sfg<<2);
      va=*(const short4*)b; vb=*(const short4*)(b+16);
    }
    *(short8v*)((char*)asA[srt]+(skt<<10)+(lam<<4))=pack8s(va,vb);
  }
  for(int i=t;i<768;i+=512){
    int srt=i/384, s6=(i-srt*384)>>6, lm=i&63, r=lm&15, g=lm>>4;
    int p=s6>>1, k2=s6&1;
    int nd=n0+srt*16+r;
    short4 va={0,0,0,0}, vb={0,0,0,0};
    if(nd<NNODE){
      const short* b=AGVh+(size_t)nd*192+(p<<6)+(k2<<5)+(g<<2);
      va=*(const short4*)b; vb=*(const short4*)(b+16);
    }
    *(short8v*)((char*)avA[srt]+(s6<<10)+(lm<<4))=pack8s(va,vb);
  }
  __syncthreads();

  // ---- P1: G1 (agg_s@Wo_s -> xs+=), G2 (agg_V@Wo_v -> xvh+=)
  {
    short8v a[4];
    #pragma unroll
    for(int kt=0;kt<4;kt++) a[kt]=*(const short8v*)((const char*)asA[rt]+(kt<<10)+(l<<4));
    #pragma unroll
    for(int ii=0;ii<2;ii++){
      int nt=wq+(ii<<2);
      f32x4 acc={0.f,0.f,0.f,0.f};
      #pragma unroll
      for(int kt=0;kt<4;kt++){
        short8v b=*(const short8v*)(P+(((size_t)(T_WOS+nt*4+kt))<<9)+(l<<3));
        acc=__builtin_amdgcn_mfma_f32_16x16x32_bf16(a[kt],b,acc,0,0,0);
      }
      int col=(nt<<4)+(l&15);
      float bv=bo_s[col];
      #pragma unroll
      for(int r=0;r<4;r++){ int row=rt*16+((l>>4)<<2)+r; xs[row][col]+=acc[r]+bv; }
    }
    #pragma unroll
    for(int ii=0;ii<3;ii++){
      int tid=wq*3+ii, p=tid>>2, nt2=tid&3;
      f32x4 acc={0.f,0.f,0.f,0.f};
      #pragma unroll
      for(int kt=0;kt<2;kt++){
        short8v a2=*(const short8v*)((const char*)avA[rt]+(((p<<1)+kt)<<10)+(l<<4));
        short8v b=*(const short8v*)(P+(((size_t)(T_WOV+nt2*2+kt))<<9)+(l<<3));
        acc=__builtin_amdgcn_mfma_f32_16x16x32_bf16(a2,b,acc,0,0,0);
      }
      int col=(p<<6)+(nt2<<4)+(l&15);
      #pragma unroll
      for(int r=0;r<4;r++){
        int row=rt*16+((l>>4)<<2)+r;
        float x=s2f(xvh[row][col]);
        xvh[row][col]=f2s(x+acc[r]);
      }
    }
  }
  __syncthreads();

  // ---- P2: LN1 stats (512 thr = 32 nodes x 16 groups)
  {
    const int nn=t>>4, g=t&15;
    float sum=0,sq=0;
    #pragma unroll
    for(int j=0;j<8;j++){ float x=xs[nn][g+16*j]; sum+=x; sq+=x*x; }
    sum=gred16(sum); sq=gred16(sq);
    float mean=sum*(1.f/128.f);
    float var=sq*(1.f/128.f)-mean*mean;
    float vsq=0;
    #pragma unroll
    for(int j=0;j<12;j++){ float x=s2f(xvh[nn][g+16*j]); vsq+=x*x; }
    vsq=gred16(vsq);
    if(g==0){ smean[nn]=mean; srs[nn]=rsqrtf(var+1e-5f); svn[nn]=rsqrtf(vsq*(1.f/64.f)+1e-5f); }
  }
  __syncthreads();

  // ---- P3a: normalize in place
  for(int i=t;i<1024;i+=512){
    int r=i>>5, c=(i&31)<<2;
    float m=smean[r], rs=srs[r];
    float4 v=*(float4*)&xs[r][c];
    v.x=(v.x-m)*rs; v.y=(v.y-m)*rs; v.z=(v.z-m)*rs; v.w=(v.w-m)*rs;
    *(float4*)&xs[r][c]=v;
  }
  for(int i=t;i<1536;i+=512){
    int r=i/48, c=(i-r*48)<<2;
    float vn=svn[r];
    short4 sv4=*(short4*)&xvh[r][c];
    sv4.x=f2s(s2f(sv4.x)*vn); sv4.y=f2s(s2f(sv4.y)*vn);
    sv4.z=f2s(s2f(sv4.z)*vn); sv4.w=f2s(s2f(sv4.w)*vn);
    *(short4*)&xvh[r][c]=sv4;
  }
  __syncthreads();
  // ---- P3b: frag-stage normalized xs/xvh
  {
    int srt=seg>>2, skt=seg&3;
    float4 va=*(const float4*)&xs[srt*16+sfr][(skt<<5)+(sfg<<2)];
    float4 vb=*(const float4*)&xs[srt*16+sfr][(skt<<5)+16+(sfg<<2)];
    *(short8v*)((char*)asA[srt]+(skt<<10)+(lam<<4))=pack8(va,vb);
  }
  for(int i=t;i<768;i+=512){
    int srt=i/384, s6=(i-srt*384)>>6, lm=i&63, r=lm&15, g=lm>>4;
    int p=s6>>1, k2=s6&1;
    short4 sa=*(const short4*)&xvh[srt*16+r][(p<<6)+(k2<<5)+(g<<2)];
    short4 sb=*(const short4*)&xvh[srt*16+r][(p<<6)+(k2<<5)+16+(g<<2)];
    *(short8v*)((char*)avA[srt]+(s6<<10)+(lm<<4))=pack8s(sa,sb);
  }
  __syncthreads();

  // ---- P4: G3 (x_s @ W1_s + b1 -> ffh)
  {
    short8v a[4];
    #pragma unroll
    for(int kt=0;kt<4;kt++) a[kt]=*(const short8v*)((const char*)asA[rt]+(kt<<10)+(l<<4));
    #pragma unroll
    for(int ii=0;ii<3;ii++){
      int nt=wq+(ii<<2);
      f32x4 acc={0.f,0.f,0.f,0.f};
      #pragma unroll
      for(int kt=0;kt<4;kt++){
        short8v b=*(const short8v*)(P+(((size_t)(T_W1S+nt*4+kt))<<9)+(l<<3));
        acc=__builtin_amdgcn_mfma_f32_16x16x32_bf16(a[kt],b,acc,0,0,0);
      }
      int col=(nt<<4)+(l&15);
      float bv=b1_s[col];
      #pragma unroll
      for(int r=0;r<4;r++){ int row=rt*16+((l>>4)<<2)+r; ffh[row][col]=f2s(acc[r]+bv); }
    }
  }
  __syncthreads();

  // ---- P5: G4 compute + silu on ffh[:,:128]
  f32x4 g4acc[3];
  {
    #pragma unroll
    for(int ii=0;ii<3;ii++){
      int tid=wq*3+ii, p=tid>>2, nt2=tid&3;
      f32x4 acc={0.f,0.f,0.f,0.f};
      #pragma unroll
      for(int kt=0;kt<2;kt++){
        short8v a2=*(const short8v*)((const char*)avA[rt]+(((p<<1)+kt)<<10)+(l<<4));
        short8v b=*(const short8v*)(P+(((size_t)(T_W1V+nt2*2+kt))<<9)+(l<<3));
        acc=__builtin_amdgcn_mfma_f32_16x16x32_bf16(a2,b,acc,0,0,0);
      }
      g4acc[ii]=acc;
    }
    for(int i=t;i<1024;i+=512){
      int r=i>>5, c=(i&31)<<2;
      short4 sv4=*(short4*)&ffh[r][c];
      float x0=s2f(sv4.x), x1=s2f(sv4.y), x2=s2f(sv4.z), x3=s2f(sv4.w);
      sv4.x=f2s(x0*sigm(x0)); sv4.y=f2s(x1*sigm(x1)); sv4.z=f2s(x2*sigm(x2)); sv4.w=f2s(x3*sigm(x3));
      *(short4*)&ffh[r][c]=sv4;
    }
  }
  __syncthreads();

  // ---- P5b: frag-stage silu(f) -> asA ; gates -> g4acc
  {
    int srt=seg>>2, skt=seg&3;
    short4 sa=*(const short4*)&ffh[srt*16+sfr][(skt<<5)+(sfg<<2)];
    short4 sb=*(const short4*)&ffh[srt*16+sfr][(skt<<5)+16+(sfg<<2)];
    *(short8v*)((char*)asA[srt]+(skt<<10)+(lam<<4))=pack8s(sa,sb);
  }
  {
    #pragma unroll
    for(int ii=0;ii<3;ii++){
      int tid=wq*3+ii, nt2=tid&3;
      int uu=(nt2<<4)+(l&15);
      #pragma unroll
      for(int r=0;r<4;r++){
        int row=rt*16+((l>>4)<<2)+r;
        g4acc[ii][r]*=sigm(s2f(ffh[row][128+uu]));
      }
    }
  }
  __syncthreads();

  // ---- P6b: gv -> ffh[:,0:192]
  {
    #pragma unroll
    for(int ii=0;ii<3;ii++){
      int tid=wq*3+ii, p=tid>>2, nt2=tid&3;
      int uu=(nt2<<4)+(l&15);
      #pragma unroll
      for(int r=0;r<4;r++){
        int row=rt*16+((l>>4)<<2)+r;
        ffh[row][(p<<6)+uu]=f2s(g4acc[ii][r]);
      }
    }
  }
  __syncthreads();
  // ---- P6c: frag-stage gv -> avA
  for(int i=t;i<768;i+=512){
    int srt=i/384, s6=(i-srt*384)>>6, lm=i&63, r=lm&15, g=lm>>4;
    int p=s6>>1, k2=s6&1;
    short4 sa=*(const short4*)&ffh[srt*16+r][(p<<6)+(k2<<5)+(g<<2)];
    short4 sb=*(const short4*)&ffh[srt*16+r][(p<<6)+(k2<<5)+16+(g<<2)];
    *(short8v*)((char*)avA[srt]+(s6<<10)+(lm<<4))=pack8s(sa,sb);
  }
  __syncthreads();

  // ---- P7: G5 (silu(f)@W2_s -> xs+=), G6 (gv@W2_v -> xvh+=)
  {
    short8v a[4];
    #pragma unroll
    for(int kt=0;kt<4;kt++) a[kt]=*(const short8v*)((const char*)asA[rt]+(kt<<10)+(l<<4));
    #pragma unroll
    for(int ii=0;ii<2;ii++){
      int nt=wq+(ii<<2);
      f32x4 acc={0.f,0.f,0.f,0.f};
      #pragma unroll
      for(int kt=0;kt<4;kt++){
        short8v b=*(const short8v*)(P+(((size_t)(T_W2S+nt*4+kt))<<9)+(l<<3));
        acc=__builtin_amdgcn_mfma_f32_16x16x32_bf16(a[kt],b,acc,0,0,0);
      }
      int col=(nt<<4)+(l&15);
      float bv=b2_s[col];
      #pragma unroll
      for(int r=0;r<4;r++){ int row=rt*16+((l>>4)<<2)+r; xs[row][col]+=acc[r]+bv; }
    }
    #pragma unroll
    for(int ii=0;ii<3;ii++){
      int tid=wq*3+ii, p=tid>>2, nt2=tid&3;
      f32x4 acc={0.f,0.f,0.f,0.f};
      #pragma unroll
      for(int kt=0;kt<2;kt++){
        short8v a2=*(const short8v*)((const char*)avA[rt]+(((p<<1)+kt)<<10)+(l<<4));
        short8v b=*(const short8v*)(P+(((size_t)(T_W2V+nt2*2+kt))<<9)+(l<<3));
        acc=__builtin_amdgcn_mfma_f32_16x16x32_bf16(a2,b,acc,0,0,0);
      }
      int col=(p<<6)+(nt2<<4)+(l&15);
      #pragma unroll
      for(int r=0;r<4;r++){
        int row=rt*16+((l>>4)<<2)+r;
        float x=s2f(xvh[row][col]);
        xvh[row][col]=f2s(x+acc[r]);
      }
    }
  }
  __syncthreads();

  // ---- P8: LN2 stats
  {
    const int nn=t>>4, g=t&15;
    float sum=0,sq=0;
    #pragma unroll
    for(int j=0;j<8;j++){ float x=xs[nn][g+16*j]; sum+=x; sq+=x*x; }
    sum=gred16(sum); sq=gred16(sq);
    float mean=sum*(1.f/128.f);
    float var=sq*(1.f/128.f)-mean*mean;
    float vsq=0;
    #pragma unroll
    for(int j=0;j<12;j++){ float x=s2f(xvh[nn][g+16*j]); vsq+=x*x; }
    vsq=gred16(vsq);
    if(g==0){ smean[nn]=mean; srs[nn]=rsqrtf(var+1e-5f); svn[nn]=rsqrtf(vsq*(1.f/64.f)+1e-5f); }
  }
  __syncthreads();

  // ---- P9: store
  for(int i=t;i<10240;i+=512){
    int nn=i/320, c=i-nn*320;
    int nd=n0+nn;
    if(nd<NNODE){
      float v;
      if(c<128) v=(xs[nn][c]-smean[nn])*srs[nn];
      else { int j=c-128; int u=j/3, k=j-u*3; v=s2f(xvh[nn][(k<<6)+u])*svn[nn]; }
      out[(size_t)nd*320+c]=v;
    }
  }
}

// ---------------------------------------------------------------------------
extern "C" void kernel_launch(void* const* d_in, const int* in_sizes, int n_in,
                              void* d_out, int out_size, void* d_ws, size_t ws_size,
                              hipStream_t stream)
{
  (void)in_sizes; (void)n_in; (void)out_size; (void)ws_size;
  const float* nf    =(const float*)d_in[0];
  const float* eattr =(const float*)d_in[1];
  const float* esh   =(const float*)d_in[2];
  const float* Wq    =(const float*)d_in[3];  const float* bq  =(const float*)d_in[4];
  const float* Wk    =(const float*)d_in[5];  const float* bk  =(const float*)d_in[6];
  const float* We    =(const float*)d_in[7];  const float* be  =(const float*)d_in[8];
  const float* Wv_s  =(const float*)d_in[9];  const float* bv_s=(const float*)d_in[10];
  const float* Wv_v  =(const float*)d_in[11];
  const float* w_ss  =(const float*)d_in[12]; const float* w_vv_s=(const float*)d_in[13];
  const float* w_ssg =(const float*)d_in[14]; const float* w_vvg =(const float*)d_in[15];
  const float* b_ms  =(const float*)d_in[16]; const float* b_mg  =(const float*)d_in[17];
  const float* w_sv  =(const float*)d_in[18]; const float* w_vs  =(const float*)d_in[19];
  const float* w_vvv =(const float*)d_in[20];
  const float* Wo_s  =(const float*)d_in[21]; const float* bo_s  =(const float*)d_in[22];
  const float* Wo_v  =(const float*)d_in[23];
  const float* W1_s  =(const float*)d_in[24]; const float* b1_s  =(const float*)d_in[25];
  const float* W1_v  =(const float*)d_in[26];
  const float* W2_s  =(const float*)d_in[27]; const float* b2_s  =(const float*)d_in[28];
  const float* W2_v  =(const float*)d_in[29];
  const int*   eidx  =(const int*)d_in[30];
  float* out=(float*)d_out;

  char* w=(char*)d_ws;
  bf16* Q    =(bf16*)w;  w+=(size_t)NNODE*256*2;
  bf16* Kb   =(bf16*)w;  w+=(size_t)NNODE*256*2;
  short* NREC2=(short*)w; w+=(size_t)NNODE*1280*2;
  float* SC  =(float*)w; w+=(size_t)NEDGE*16*4;
  float* ESHs=(float*)w; w+=(size_t)NEDGE*4*4;
  float* ATTs=(float*)w; w+=(size_t)NEDGE*4;
  short* AGSh=(short*)w; w+=(size_t)NNODE*128*2;
  short* AGVh=(short*)w; w+=(size_t)NNODE*192*2;
  short* P   =(short*)w; w+=(size_t)T_TOT*512*2;
  int* COUNTS=(int*)w;   w+=(size_t)NNODE*4;
  int* OFFb  =(int*)w;   w+=(size_t)(NNODE+1)*4;
  int* CURSOR=(int*)w;   w+=(size_t)NNODE*4;
  int* EORDb =(int*)w;   w+=(size_t)NEDGE*4;
  int* SRCs  =(int*)w;   w+=(size_t)NEDGE*4;
  int* BSUM  =(int*)w;   w+=(size_t)256*4;
  int* BOFF  =(int*)w;   w+=(size_t)256*4;
  // DSTs aliases ATTs: written by k_scatter, read by k3; ATTs written later
  // by k5. Same-stream ordering; keeps ws under the 256MiB budget.
  int* DSTs = (int*)ATTs;

  hipMemsetAsync(COUNTS,0,(size_t)NNODE*4,stream);

  k_prep    <<<T_TOT,64,0,stream>>>(Wo_s,Wo_v,W1_s,W1_v,W2_s,W2_v,We,
                                    Wq,Wk,Wv_s,w_ss,w_ssg,w_sv,
                                    Wv_v,w_vv_s,w_vvg,w_vs,w_vvv,P);
  k_hist    <<<(NEDGE+255)/256,256,0,stream>>>(eidx,COUNTS);
  k_scan1   <<<SCAN_NB,256,0,stream>>>(COUNTS,BSUM);
  k_scan2   <<<1,256,0,stream>>>(BSUM,BOFF);
  k_scan3   <<<SCAN_NB,256,0,stream>>>(COUNTS,BOFF,OFFb,CURSOR);
  k_scatter <<<(NEDGE+255)/256,256,0,stream>>>(eidx,esh,CURSOR,EORDb,SRCs,DSTs,ESHs);
  k1_mfma   <<<NNODE/16,256,0,stream>>>(nf,P,bq,bk,bv_s,Q,Kb,NREC2);
  k2_mfma   <<<NNODE/16,256,0,stream>>>(nf,P,NREC2);
  k3_mfma   <<<NEDGE/16,256,0,stream>>>(eattr,EORDb,SRCs,DSTs,P,be,Q,Kb,SC);
  k5_att    <<<NNODE/4,256,0,stream>>>(SC,OFFb,ATTs);
  k6_agg    <<<NNODE/4,256,0,stream>>>(SRCs,ESHs,NREC2,ATTs,OFFb,b_ms,b_mg,AGSh,AGVh);
  k7_mfma   <<<K7NBLK,512,0,stream>>>(nf,AGSh,AGVh,P,bo_s,b1_s,b2_s,out);
}

// Round 16
// 456.525 us; speedup vs baseline: 1.0283x; 1.0283x over previous
//
#include <hip/hip_runtime.h>
#include <hip/hip_bf16.h>

#define NNODE 50000
#define NEDGE 250000

typedef __hip_bfloat16 bf16;
typedef __attribute__((ext_vector_type(8))) short short8v;
typedef __attribute__((ext_vector_type(4))) float f32x4;

__device__ __forceinline__ float b2f(bf16 x){ return __bfloat162float(x); }
__device__ __forceinline__ bf16  f2b(float x){ return __float2bfloat16(x); }
__device__ __forceinline__ short f2s(float x){ bf16 h=f2b(x); short s; __builtin_memcpy(&s,&h,2); return s; }
__device__ __forceinline__ float s2f(short s){ bf16 h; __builtin_memcpy(&h,&s,2); return b2f(h); }
__device__ __forceinline__ float sigm(float x){ return 1.0f/(1.0f+__expf(-x)); }
__device__ __forceinline__ float wred64(float v){
  #pragma unroll
  for(int o=32;o>0;o>>=1) v+=__shfl_xor(v,o,64);
  return v;
}
__device__ __forceinline__ float gred16(float v){
  v+=__shfl_xor(v,1,64); v+=__shfl_xor(v,2,64); v+=__shfl_xor(v,4,64); v+=__shfl_xor(v,8,64);
  return v;
}
__device__ __forceinline__ int ired64(int v){
  #pragma unroll
  for(int o=32;o>0;o>>=1) v+=__shfl_xor(v,o,64);
  return v;
}
// byte offset of element (row r, k) inside a multi-kt A-frag region (kt stride 1024B)
__device__ __forceinline__ int fragOff(int r, int k){
  int kt=k>>5, k32=k&31, half=k32>>4, g=(k32&15)>>2, j=k32&3;
  return (kt<<10)+((r+(g<<4))<<4)+(half<<3)+(j<<1);
}
__device__ __forceinline__ short8v pack8(float4 a, float4 b){
  short8v s; s[0]=f2s(a.x);s[1]=f2s(a.y);s[2]=f2s(a.z);s[3]=f2s(a.w);
  s[4]=f2s(b.x);s[5]=f2s(b.y);s[6]=f2s(b.z);s[7]=f2s(b.w); return s;
}
__device__ __forceinline__ short8v pack8s(short4 a, short4 b){
  short8v s; s[0]=a.x;s[1]=a.y;s[2]=a.z;s[3]=a.w;s[4]=b.x;s[5]=b.y;s[6]=b.z;s[7]=b.w; return s;
}

// ---------------------------------------------------------------------------
// Weight-prep tile map (each tile 1KB: 64 lanes x 8 bf16)
// ---------------------------------------------------------------------------
#define T_WOS 0
#define T_WOV 32
#define T_W1S 40
#define T_W1V 88
#define T_W2S 96
#define T_W2V 128
#define T_WE  136
#define T_WQ  168
#define T_WK  232
#define T_WVS 296
#define T_WSS 328
#define T_WSSG 360
#define T_WSV 376
#define T_WVV 392
#define T_WVVS 400
#define T_WVVG 416
#define T_WVS2 424
#define T_WVVV 432
#define T_TOT 440

__global__ __launch_bounds__(64) void k_prep(
  const float* __restrict__ Wo_s, const float* __restrict__ Wo_v,
  const float* __restrict__ W1_s, const float* __restrict__ W1_v,
  const float* __restrict__ W2_s, const float* __restrict__ W2_v,
  const float* __restrict__ WeM,
  const float* __restrict__ Wq, const float* __restrict__ Wk,
  const float* __restrict__ Wv_s,
  const float* __restrict__ w_ss, const float* __restrict__ w_ssg,
  const float* __restrict__ w_sv,
  const float* __restrict__ Wv_v, const float* __restrict__ w_vv_s,
  const float* __restrict__ w_vvg, const float* __restrict__ w_vs,
  const float* __restrict__ w_vvv,
  short* __restrict__ P)
{
  const int T=blockIdx.x, l=threadIdx.x;
  const float* W; int N, KT, lt;
  if(T<T_WOV){ W=Wo_s; N=128; KT=4; lt=T; }
  else if(T<T_W1S){ W=Wo_v; N=64; KT=2; lt=T-T_WOV; }
  else if(T<T_W1V){ W=W1_s; N=192; KT=4; lt=T-T_W1S; }
  else if(T<T_W2S){ W=W1_v; N=64; KT=2; lt=T-T_W1V; }
  else if(T<T_W2V){ W=W2_s; N=128; KT=4; lt=T-T_W2S; }
  else if(T<T_WE){ W=W2_v; N=64; KT=2; lt=T-T_W2V; }
  else if(T<T_WQ){ W=WeM; N=256; KT=2; lt=T-T_WE; }
  else if(T<T_WK){ W=Wq; N=256; KT=4; lt=T-T_WQ; }
  else if(T<T_WVS){ W=Wk; N=256; KT=4; lt=T-T_WK; }
  else if(T<T_WSS){ W=Wv_s; N=128; KT=4; lt=T-T_WVS; }
  else if(T<T_WSSG){ W=w_ss; N=128; KT=4; lt=T-T_WSS; }
  else if(T<T_WSV){ W=w_ssg; N=64; KT=4; lt=T-T_WSSG; }
  else if(T<T_WVV){ W=w_sv; N=64; KT=4; lt=T-T_WSV; }
  else if(T<T_WVVS){ W=Wv_v; N=64; KT=2; lt=T-T_WVV; }
  else if(T<T_WVVG){ W=w_vv_s; N=128; KT=2; lt=T-T_WVVS; }
  else if(T<T_WVS2){ W=w_vvg; N=64; KT=2; lt=T-T_WVVG; }
  else if(T<T_WVVV){ W=w_vs; N=64; KT=2; lt=T-T_WVS2; }
  else { W=w_vvv; N=64; KT=2; lt=T-T_WVVV; }
  const int nt=lt/KT, kt=lt-nt*KT;
  const int col=nt*16+(l&15);
  short8v o;
  #pragma unroll
  for(int j=0;j<8;j++){
    int k=kt*32+((j>>2)<<4)+((l>>4)<<2)+(j&3);
    o[j]=f2s(W[(size_t)k*N+col]);
  }
  *(short8v*)(P+((size_t)T<<9)+(l<<3))=o;
}

// ---------------------------------------------------------------------------
// K1 (MFMA): Q,K (bf16) and NREC g0 = {S1(128), S2(64), sv(64)}
// ---------------------------------------------------------------------------
__global__ __launch_bounds__(256) void k1_mfma(
  const float* __restrict__ nf, const short* __restrict__ P,
  const float* __restrict__ bq, const float* __restrict__ bk,
  const float* __restrict__ bvs,
  bf16* __restrict__ Q, bf16* __restrict__ K, short* __restrict__ NREC2)
{
  __shared__ __align__(16) short nsF[4*512];
  __shared__ __align__(16) short vsF[4*512];
  const int t=threadIdx.x, l=t&63, w=t>>6;
  const int n0=blockIdx.x*16;
  for(int i=t;i<512;i+=256){
    int r=i>>5, c=(i&31)<<2;
    const float4 v=*(const float4*)&nf[(size_t)(n0+r)*320+c];
    short4 s; s.x=f2s(v.x); s.y=f2s(v.y); s.z=f2s(v.z); s.w=f2s(v.w);
    *(short4*)((char*)nsF+fragOff(r,c))=s;
  }
  __syncthreads();
  short8v a[4];
  #pragma unroll
  for(int kt=0;kt<4;kt++) a[kt]=*(const short8v*)((const char*)nsF+(kt<<10)+(l<<4));
  #pragma unroll
  for(int ii=0;ii<4;ii++){
    int nt=w+(ii<<2);
    f32x4 accq={0.f,0.f,0.f,0.f}, acck={0.f,0.f,0.f,0.f};
    #pragma unroll
    for(int kt=0;kt<4;kt++){
      short8v bq8=*(const short8v*)(P+(((size_t)(T_WQ+nt*4+kt))<<9)+(l<<3));
      short8v bk8=*(const short8v*)(P+(((size_t)(T_WK+nt*4+kt))<<9)+(l<<3));
      accq=__builtin_amdgcn_mfma_f32_16x16x32_bf16(a[kt],bq8,accq,0,0,0);
      acck=__builtin_amdgcn_mfma_f32_16x16x32_bf16(a[kt],bk8,acck,0,0,0);
    }
    int col=(nt<<4)+(l&15);
    float bqs=bq[col], bks=bk[col];
    #pragma unroll
    for(int r=0;r<4;r++){
      int row=((l>>4)<<2)+r;
      Q[(size_t)(n0+row)*256+col]=f2b(accq[r]+bqs);
      K[(size_t)(n0+row)*256+col]=f2b(acck[r]+bks);
    }
  }
  #pragma unroll
  for(int ii=0;ii<2;ii++){
    int nt=w+(ii<<2);
    f32x4 acc={0.f,0.f,0.f,0.f};
    #pragma unroll
    for(int kt=0;kt<4;kt++){
      short8v b=*(const short8v*)(P+(((size_t)(T_WVS+nt*4+kt))<<9)+(l<<3));
      acc=__builtin_amdgcn_mfma_f32_16x16x32_bf16(a[kt],b,acc,0,0,0);
    }
    int col=(nt<<4)+(l&15);
    float bv=bvs[col];
    #pragma unroll
    for(int r=0;r<4;r++){
      int row=((l>>4)<<2)+r;
      *(short*)((char*)vsF+fragOff(row,col))=f2s(acc[r]+bv);
    }
  }
  __syncthreads();
  #pragma unroll
  for(int kt=0;kt<4;kt++) a[kt]=*(const short8v*)((const char*)vsF+(kt<<10)+(l<<4));
  #pragma unroll
  for(int ii=0;ii<4;ii++){
    int nt=w+(ii<<2);
    int bt;
    if(nt<8) bt=T_WSS+nt*4;
    else if(nt<12) bt=T_WSSG+(nt-8)*4;
    else bt=T_WSV+(nt-12)*4;
    f32x4 acc={0.f,0.f,0.f,0.f};
    #pragma unroll
    for(int kt=0;kt<4;kt++){
      short8v b=*(const short8v*)(P+(((size_t)(bt+kt))<<9)+(l<<3));
      acc=__builtin_amdgcn_mfma_f32_16x16x32_bf16(a[kt],b,acc,0,0,0);
    }
    int col=(nt<<4)+(l&15);
    int lane, sslot;
    if(nt<8){ lane=col&63; sslot=(col>=64)?1:0; }
    else if(nt<12){ lane=col-128; sslot=2; }
    else { lane=col-192; sslot=3; }
    #pragma unroll
    for(int r=0;r<4;r++){
      int row=((l>>4)<<2)+r;
      NREC2[(size_t)(n0+row)*1280 + (lane<<2) + sslot]=f2s(acc[r]);
    }
  }
}

// ---------------------------------------------------------------------------
// K2 (MFMA): NREC groups g1..g4 = {D1(3x128), D2(3x64), Wvs(3x64), Cn(3x64)}
// ---------------------------------------------------------------------------
__global__ __launch_bounds__(256) void k2_mfma(
  const float* __restrict__ nf, const short* __restrict__ P,
  short* __restrict__ NREC2)
{
  __shared__ __align__(16) short nvF[6*512];
  __shared__ __align__(16) short vvF[6*512];
  const int t=threadIdx.x, l=t&63, w=t>>6;
  const int n0=blockIdx.x*16;
  for(int i=t;i<3072;i+=256){
    int r=i/192, c=i-r*192;
    int v=c/3, k=c-3*v;
    float x=nf[(size_t)(n0+r)*320+128+c];
    *(short*)((char*)nvF+(k<<11)+fragOff(r,v))=f2s(x);
  }
  __syncthreads();
  #pragma unroll
  for(int jj=0;jj<3;jj++){
    int job=w+(jj<<2);
    int p=job>>2, nt=job&3;
    f32x4 acc={0.f,0.f,0.f,0.f};
    #pragma unroll
    for(int kt=0;kt<2;kt++){
      short8v a2=*(const short8v*)((const char*)nvF+(p<<11)+(kt<<10)+(l<<4));
      short8v b=*(const short8v*)(P+(((size_t)(T_WVV+nt*2+kt))<<9)+(l<<3));
      acc=__builtin_amdgcn_mfma_f32_16x16x32_bf16(a2,b,acc,0,0,0);
    }
    int col=(nt<<4)+(l&15);
    #pragma unroll
    for(int r=0;r<4;r++){
      int row=((l>>4)<<2)+r;
      *(short*)((char*)vvF+(p<<11)+fragOff(row,col))=f2s(acc[r]);
    }
  }
  __syncthreads();
  #pragma unroll
  for(int jj=0;jj<15;jj++){
    int job=w+(jj<<2);
    int p=job/20, r20=job-p*20;
    int nt, bt, G0;
    if(r20<8){ nt=r20; bt=T_WVVS+nt*2; G0=0; }
    else if(r20<12){ nt=r20-8; bt=T_WVVG+nt*2; G0=1; }
    else if(r20<16){ nt=r20-12; bt=T_WVS2+nt*2; G0=2; }
    else { nt=r20-16; bt=T_WVVV+nt*2; G0=3; }
    f32x4 acc={0.f,0.f,0.f,0.f};
    #pragma unroll
    for(int kt=0;kt<2;kt++){
      short8v a2=*(const short8v*)((const char*)vvF+(p<<11)+(kt<<10)+(l<<4));
      short8v b=*(const short8v*)(P+(((size_t)(bt+kt))<<9)+(l<<3));
      acc=__builtin_amdgcn_mfma_f32_16x16x32_bf16(a2,b,acc,0,0,0);
    }
    int col=(nt<<4)+(l&15);
    int G;
    if(G0==0)      G = p*2 + (col>=64 ? 1 : 0);
    else if(G0==1) G = 6 + p;
    else if(G0==2) G = 9 + p;
    else           G = 12 + p;
    int lane = col & 63;
    int addr = ((1+(G>>2))<<8) + (lane<<2) + (G&3);
    #pragma unroll
    for(int r=0;r<4;r++){
      int row=((l>>4)<<2)+r;
      NREC2[(size_t)(n0+row)*1280 + addr]=f2s(acc[r]);
    }
  }
}

// ---------------------------------------------------------------------------
// Sort-by-dst: histogram -> 3-kernel scan -> scatter (index + payload).
// ---------------------------------------------------------------------------
__global__ __launch_bounds__(256) void k_hist(const int* __restrict__ eidx, int* __restrict__ counts){
  int e=blockIdx.x*256+threadIdx.x;
  if(e<NEDGE) atomicAdd(&counts[eidx[NEDGE+e]],1);
}

#define SCAN_NB 196

__global__ __launch_bounds__(256) void k_scan1(const int* __restrict__ counts, int* __restrict__ bsum){
  const int t=threadIdx.x, ln=t&63, wid=t>>6;
  int idx=blockIdx.x*256+t;
  int v=(idx<NNODE)?counts[idx]:0;
  int s=ired64(v);
  __shared__ int ws[4];
  if(ln==0) ws[wid]=s;
  __syncthreads();
  if(t==0) bsum[blockIdx.x]=ws[0]+ws[1]+ws[2]+ws[3];
}

__global__ __launch_bounds__(256) void k_scan2(const int* __restrict__ bsum, int* __restrict__ boff){
  const int t=threadIdx.x, ln=t&63, wid=t>>6;
  int v=(t<SCAN_NB)?bsum[t]:0;
  int incl=v;
  #pragma unroll
  for(int o=1;o<64;o<<=1){ int x=__shfl_up(incl,o,64); if(ln>=o) incl+=x; }
  __shared__ int wtot[4], wpre[4];
  if(ln==63) wtot[wid]=incl;
  __syncthreads();
  if(t==0){ int s=0; for(int k=0;k<4;k++){ wpre[k]=s; s+=wtot[k]; } }
  __syncthreads();
  if(t<SCAN_NB) boff[t]=wpre[wid]+incl-v;
}

__global__ __launch_bounds__(256) void k_scan3(const int* __restrict__ counts, const int* __restrict__ boff,
                                               int* __restrict__ off, int* __restrict__ cursor){
  const int t=threadIdx.x, ln=t&63, wid=t>>6;
  int idx=blockIdx.x*256+t;
  int v=(idx<NNODE)?counts[idx]:0;
  int incl=v;
  #pragma unroll
  for(int o=1;o<64;o<<=1){ int x=__shfl_up(incl,o,64); if(ln>=o) incl+=x; }
  __shared__ int wtot[4], wpre[4];
  if(ln==63) wtot[wid]=incl;
  __syncthreads();
  if(t==0){ int s=0; for(int k=0;k<4;k++){ wpre[k]=s; s+=wtot[k]; } }
  __syncthreads();
  int excl=boff[blockIdx.x]+wpre[wid]+incl-v;
  if(idx<NNODE){ off[idx]=excl; cursor[idx]=excl; }
  if(blockIdx.x==SCAN_NB-1 && t==255) off[NNODE]=NEDGE;
}

__global__ __launch_bounds__(256) void k_scatter(
  const int* __restrict__ eidx, const float* __restrict__ esh,
  int* __restrict__ cursor, int* __restrict__ eord,
  int* __restrict__ srcs, int* __restrict__ dsts, float* __restrict__ eshs)
{
  int e=blockIdx.x*256+threadIdx.x;
  if(e<NEDGE){
    int d=eidx[NEDGE+e];
    int pos=atomicAdd(&cursor[d],1);
    eord[pos]=e;
    srcs[pos]=eidx[e];
    dsts[pos]=d;
    *(float4*)&eshs[(size_t)pos*4]=*(const float4*)&esh[(size_t)e*4];
  }
}

// ---------------------------------------------------------------------------
// K3 (MFMA, sorted order): ef = edge_attr@We + be; scores -> SC (sorted).
// ---------------------------------------------------------------------------
__global__ __launch_bounds__(256) void k3_mfma(
  const float* __restrict__ eattr,
  const int* __restrict__ EORD, const int* __restrict__ SRCs, const int* __restrict__ DSTs,
  const short* __restrict__ P, const float* __restrict__ be,
  const bf16* __restrict__ Q, const bf16* __restrict__ K,
  float* __restrict__ SC)
{
  __shared__ __align__(16) short aeF[2*512];
  __shared__ __align__(16) float ef[16][260];
  __shared__ int sed[16], ssrc[16], sdst[16];
  const int t=threadIdx.x, l=t&63, w=t>>6;
  const int e0=blockIdx.x*16;
  if(t<16){
    sed[t]=EORD[e0+t];
    ssrc[t]=SRCs[e0+t];
    sdst[t]=DSTs[e0+t];
  }
  __syncthreads();
  {
    int r=t>>4, c4=(t&15)<<2;
    const float4 v=*(const float4*)&eattr[(size_t)sed[r]*64+c4];
    short4 s; s.x=f2s(v.x); s.y=f2s(v.y); s.z=f2s(v.z); s.w=f2s(v.w);
    *(short4*)((char*)aeF+fragOff(r,c4))=s;
  }
  __syncthreads();
  {
    short8v a0=*(const short8v*)((const char*)aeF+(l<<4));
    short8v a1=*(const short8v*)((const char*)aeF+1024+(l<<4));
    #pragma unroll
    for(int ii=0;ii<4;ii++){
      int nt=w+(ii<<2);
      f32x4 acc={0.f,0.f,0.f,0.f};
      short8v b0=*(const short8v*)(P+(((size_t)(T_WE+nt*2+0))<<9)+(l<<3));
      short8v b1=*(const short8v*)(P+(((size_t)(T_WE+nt*2+1))<<9)+(l<<3));
      acc=__builtin_amdgcn_mfma_f32_16x16x32_bf16(a0,b0,acc,0,0,0);
      acc=__builtin_amdgcn_mfma_f32_16x16x32_bf16(a1,b1,acc,0,0,0);
      int col=(nt<<4)+(l&15);
      float bv=be[col];
      #pragma unroll
      for(int r=0;r<4;r++){ int row=((l>>4)<<2)+r; ef[row][col]=acc[r]+bv; }
    }
  }
  __syncthreads();
  {
    const int h=l&15, qt=l>>4;
    const int ch=h*16+(qt<<2);
    #pragma unroll
    for(int j=0;j<4;j++){
      int el=w*4+j;
      int s=ssrc[el], d=sdst[el];
      short4 qs=*(const short4*)((const short*)Q+(size_t)d*256+ch);
      short4 ks=*(const short4*)((const short*)K+(size_t)s*256+ch);
      const float4 e4=*(const float4*)&ef[el][ch];
      float p = s2f(qs.x)*(s2f(ks.x)+e4.x)
              + s2f(qs.y)*(s2f(ks.y)+e4.y)
              + s2f(qs.z)*(s2f(ks.z)+e4.z)
              + s2f(qs.w)*(s2f(ks.w)+e4.w);
      p += __shfl_xor(p,16,64);
      p += __shfl_xor(p,32,64);
      if(qt==0) SC[(size_t)(e0+el)*16+h]=p*0.25f;
    }
  }
}

// ---------------------------------------------------------------------------
// K5: per-edge attention weight -> ATTs. SC is in sorted order -> streamed.
// ---------------------------------------------------------------------------
__global__ __launch_bounds__(256) void k5_att(
  const float* __restrict__ SC, const int* __restrict__ OFF,
  float* __restrict__ ATTs)
{
  const int l=threadIdx.x&63;
  const int n=blockIdx.x*4+(threadIdx.x>>6);
  const int beg=OFF[n], end=OFF[n+1];
  const int j=l>>4, h=l&15;
  float mh=-1e30f;
  for(int i=beg+j;i<end;i+=4) mh=fmaxf(mh, SC[(size_t)i*16+h]);
  mh=fmaxf(mh,__shfl_xor(mh,16,64));
  mh=fmaxf(mh,__shfl_xor(mh,32,64));
  float dh=0.f;
  for(int i=beg+j;i<end;i+=4) dh+=__expf(SC[(size_t)i*16+h]-mh);
  dh+=__shfl_xor(dh,16,64);
  dh+=__shfl_xor(dh,32,64);
  float rdh=(end>beg)?1.f/dh:0.f;
  for(int i0=beg;i0<end;i0+=4){
    int i=i0+j;
    float a=0.f; bool act=(i<end);
    if(act) a=__expf(SC[(size_t)i*16+h]-mh)*rdh;
    a=gred16(a);
    if(h==0 && act) ATTs[i]=a*(1.f/16.f);
  }
}

// ---------------------------------------------------------------------------
// K6: per-dst-node aggregation. One wave per node, 4 nodes/block.
// Aggregates written as bf16 (AGSh/AGVh).
// ---------------------------------------------------------------------------
__global__ __launch_bounds__(256) void k6_agg(
  const int* __restrict__ SRCs, const float* __restrict__ ESHs,
  const short* __restrict__ NREC2, const float* __restrict__ ATTs,
  const int* __restrict__ OFF,
  const float* __restrict__ b_ms, const float* __restrict__ b_mg,
  short* __restrict__ AGSh, short* __restrict__ AGVh)
{
  const int l = threadIdx.x & 63;
  const int n = blockIdx.x*4 + (threadIdx.x>>6);
  const int beg=OFF[n], end=OFF[n+1];
  const float bmsa=b_ms[l], bmsb=b_ms[64+l], bmgv=b_mg[l];

  float as0=0.f,as1=0.f,av0acc=0.f,av1acc=0.f,av2acc=0.f;
  for(int i=beg;i<end;i++){
    const int s=SRCs[i];
    const float att=ATTs[i];
    const float4 sh4=*(const float4*)&ESHs[(size_t)i*4];
    const float shs=sh4.x, sh0=sh4.y, sh1=sh4.z, sh2=sh4.w;

    const short* R = NREC2 + (size_t)s*1280 + (l<<2);
    const short4 q0=*(const short4*)(R);
    const short4 q1=*(const short4*)(R+256);
    const short4 q2=*(const short4*)(R+512);
    const short4 q3=*(const short4*)(R+768);
    const short4 q4=*(const short4*)(R+1024);

    float msa = shs*s2f(q0.x) + s2f(q1.x)*sh0 + s2f(q1.z)*sh1 + s2f(q2.x)*sh2 + bmsa;
    float msb = shs*s2f(q0.y) + s2f(q1.y)*sh0 + s2f(q1.w)*sh1 + s2f(q2.y)*sh2 + bmsb;
    float mgv = shs*s2f(q0.z) + s2f(q2.z)*sh0 + s2f(q2.w)*sh1 + s2f(q3.x)*sh2 + bmgv;

    float sum = wred64(msa+msb+mgv);
    float sq  = wred64(msa*msa+msb*msb+mgv*mgv);
    float mean = sum*(1.f/192.f);
    float var  = sq*(1.f/192.f) - mean*mean;
    float rs   = rsqrtf(var + 1e-5f);

    const float svv=s2f(q0.w);
    const float w0=s2f(q3.y), w1=s2f(q3.z), w2=s2f(q3.w);
    const float c0=s2f(q4.x), c1=s2f(q4.y), c2=s2f(q4.z);
    float cr0 = c1*sh2 - c2*sh1;
    float cr1 = c2*sh0 - c0*sh2;
    float cr2 = c0*sh1 - c1*sh0;
    float mv0 = svv*sh0 + shs*w0 + cr0;
    float mv1 = svv*sh1 + shs*w1 + cr1;
    float mv2 = svv*sh2 + shs*w2 + cr2;
    float vsq = wred64(mv0*mv0+mv1*mv1+mv2*mv2);
    float vn  = rsqrtf(vsq*(1.f/64.f) + 1e-5f);

    float sga=(msa-mean)*rs, sgb=(msb-mean)*rs, sgg=(mgv-mean)*rs;
    float wV = vn * sigm(sgg) * att;
    as0 += sga*sigm(sga)*att;
    as1 += sgb*sigm(sgb)*att;
    av0acc += mv0*wV;
    av1acc += mv1*wV;
    av2acc += mv2*wV;
  }
  AGSh[(size_t)n*128+l]     =f2s(as0);
  AGSh[(size_t)n*128+64+l]  =f2s(as1);
  AGVh[(size_t)n*192+l]     =f2s(av0acc);
  AGVh[(size_t)n*192+64+l]  =f2s(av1acc);
  AGVh[(size_t)n*192+128+l] =f2s(av2acc);
}

// ---------------------------------------------------------------------------
// K7 (MFMA, v5): final node update. 16 nodes/block, 4 waves (R13 geometry),
// bf16 aggregate inputs (direct short4 frag staging). LDS ~32KB.
// ---------------------------------------------------------------------------
__global__ __launch_bounds__(256) void k7_mfma(
  const float* __restrict__ nf,
  const short* __restrict__ AGSh, const short* __restrict__ AGVh,
  const short* __restrict__ P,
  const float* __restrict__ bo_s, const float* __restrict__ b1_s, const float* __restrict__ b2_s,
  float* __restrict__ out)
{
  __shared__ float xs[16][132];
  __shared__ short xvh[16][200];
  __shared__ short ffh[16][204];
  __shared__ __align__(16) short asA[4*512];
  __shared__ __align__(16) short avA[6*512];
  __shared__ float smean[16], srs[16], svn[16];
  const int t=threadIdx.x, l=t&63, w=t>>6;
  const int n0=blockIdx.x*16;
  const int lam=t&63, kt4=t>>6;
  const int fr=lam&15, fg=lam>>4;

  // ---- P0: residuals + frag-stage AGSh/AGVh (bf16, direct short4 copies)
  for(int i=t;i<2048;i+=256){ int r=i>>7,c=i&127; xs[r][c]=nf[(size_t)(n0+r)*320+c]; }
  for(int i=t;i<3072;i+=256){ int r=i/192,cc=i-r*192; int k=cc>>6,u=cc&63; xvh[r][cc]=f2s(nf[(size_t)(n0+r)*320+128+u*3+k]); }
  {
    const short* base=AGSh+(size_t)(n0+fr)*128 + (kt4<<5) + (fg<<2);
    short4 va=*(const short4*)base, vb=*(const short4*)(base+16);
    *(short8v*)((char*)asA+(kt4<<10)+(lam<<4))=pack8s(va,vb);
  }
  for(int i=t;i<384;i+=256){
    int seg=i>>6, lm=i&63, r=lm&15, g=lm>>4;
    int p=seg>>1, k2=seg&1;
    const short* base=AGVh+(size_t)(n0+r)*192 + (p<<6) + (k2<<5) + (g<<2);
    short4 va=*(const short4*)base, vb=*(const short4*)(base+16);
    *(short8v*)((char*)avA+(seg<<10)+(lm<<4))=pack8s(va,vb);
  }
  __syncthreads();

  // ---- P1: G1 (agg_s@Wo_s -> xs+=), G2 (agg_V@Wo_v -> xvh+=)
  {
    short8v a[4];
    #pragma unroll
    for(int kt=0;kt<4;kt++) a[kt]=*(const short8v*)((const char*)asA+(kt<<10)+(l<<4));
    #pragma unroll
    for(int ii=0;ii<2;ii++){
      int nt=w+(ii<<2);
      f32x4 acc={0.f,0.f,0.f,0.f};
      #pragma unroll
      for(int kt=0;kt<4;kt++){
        short8v b=*(const short8v*)(P+(((size_t)(T_WOS+nt*4+kt))<<9)+(l<<3));
        acc=__builtin_amdgcn_mfma_f32_16x16x32_bf16(a[kt],b,acc,0,0,0);
      }
      int col=(nt<<4)+(l&15);
      float bv=bo_s[col];
      #pragma unroll
      for(int r=0;r<4;r++){ int row=((l>>4)<<2)+r; xs[row][col]+=acc[r]+bv; }
    }
    #pragma unroll
    for(int ii=0;ii<3;ii++){
      int tid=w*3+ii, p=tid>>2, nt2=tid&3;
      f32x4 acc={0.f,0.f,0.f,0.f};
      #pragma unroll
      for(int kt=0;kt<2;kt++){
        short8v a2=*(const short8v*)((const char*)avA+(((p<<1)+kt)<<10)+(l<<4));
        short8v b=*(const short8v*)(P+(((size_t)(T_WOV+nt2*2+kt))<<9)+(l<<3));
        acc=__builtin_amdgcn_mfma_f32_16x16x32_bf16(a2,b,acc,0,0,0);
      }
      int col=(p<<6)+(nt2<<4)+(l&15);
      #pragma unroll
      for(int r=0;r<4;r++){
        int row=((l>>4)<<2)+r;
        float x=s2f(xvh[row][col]);
        xvh[row][col]=f2s(x+acc[r]);
      }
    }
  }
  __syncthreads();

  // ---- P2: LN1 stats
  {
    const int nn=t>>4, g=t&15;
    float sum=0,sq=0;
    #pragma unroll
    for(int j=0;j<8;j++){ float x=xs[nn][g+16*j]; sum+=x; sq+=x*x; }
    sum=gred16(sum); sq=gred16(sq);
    float mean=sum*(1.f/128.f);
    float var=sq*(1.f/128.f)-mean*mean;
    float vsq=0;
    #pragma unroll
    for(int j=0;j<12;j++){ float x=s2f(xvh[nn][g+16*j]); vsq+=x*x; }
    vsq=gred16(vsq);
    if(g==0){ smean[nn]=mean; srs[nn]=rsqrtf(var+1e-5f); svn[nn]=rsqrtf(vsq*(1.f/64.f)+1e-5f); }
  }
  __syncthreads();

  // ---- P3a: normalize in place
  for(int i=t;i<512;i+=256){
    int r=i>>5, c=(i&31)<<2;
    float m=smean[r], rs=srs[r];
    float4 v=*(float4*)&xs[r][c];
    v.x=(v.x-m)*rs; v.y=(v.y-m)*rs; v.z=(v.z-m)*rs; v.w=(v.w-m)*rs;
    *(float4*)&xs[r][c]=v;
  }
  for(int i=t;i<768;i+=256){
    int r=i/48, c=(i-r*48)<<2;
    float vn=svn[r];
    short4 sv4=*(short4*)&xvh[r][c];
    sv4.x=f2s(s2f(sv4.x)*vn); sv4.y=f2s(s2f(sv4.y)*vn);
    sv4.z=f2s(s2f(sv4.z)*vn); sv4.w=f2s(s2f(sv4.w)*vn);
    *(short4*)&xvh[r][c]=sv4;
  }
  __syncthreads();
  // ---- P3b: frag-stage normalized xs/xvh
  {
    float4 va=*(const float4*)&xs[fr][(kt4<<5)+(fg<<2)];
    float4 vb=*(const float4*)&xs[fr][(kt4<<5)+16+(fg<<2)];
    *(short8v*)((char*)asA+(kt4<<10)+(lam<<4))=pack8(va,vb);
  }
  for(int i=t;i<384;i+=256){
    int seg=i>>6, lm=i&63, r=lm&15, g=lm>>4;
    int p=seg>>1, k2=seg&1;
    short4 sa=*(const short4*)&xvh[r][(p<<6)+(k2<<5)+(g<<2)];
    short4 sb=*(const short4*)&xvh[r][(p<<6)+(k2<<5)+16+(g<<2)];
    *(short8v*)((char*)avA+(seg<<10)+(lm<<4))=pack8s(sa,sb);
  }
  __syncthreads();

  // ---- P4: G3 (x_s @ W1_s + b1 -> ffh bf16)
  {
    short8v a[4];
    #pragma unroll
    for(int kt=0;kt<4;kt++) a[kt]=*(const short8v*)((const char*)asA+(kt<<10)+(l<<4));
    #pragma unroll
    for(int ii=0;ii<3;ii++){
      int nt=w+(ii<<2);
      f32x4 acc={0.f,0.f,0.f,0.f};
      #pragma unroll
      for(int kt=0;kt<4;kt++){
        short8v b=*(const short8v*)(P+(((size_t)(T_W1S+nt*4+kt))<<9)+(l<<3));
        acc=__builtin_amdgcn_mfma_f32_16x16x32_bf16(a[kt],b,acc,0,0,0);
      }
      int col=(nt<<4)+(l&15);
      float bv=b1_s[col];
      #pragma unroll
      for(int r=0;r<4;r++){ int row=((l>>4)<<2)+r; ffh[row][col]=f2s(acc[r]+bv); }
    }
  }
  __syncthreads();

  // ---- P5: G4 compute + silu on ffh[:,:128]
  f32x4 g4acc[3];
  {
    #pragma unroll
    for(int ii=0;ii<3;ii++){
      int tid=w*3+ii, p=tid>>2, nt2=tid&3;
      f32x4 acc={0.f,0.f,0.f,0.f};
      #pragma unroll
      for(int kt=0;kt<2;kt++){
        short8v a2=*(const short8v*)((const char*)avA+(((p<<1)+kt)<<10)+(l<<4));
        short8v b=*(const short8v*)(P+(((size_t)(T_W1V+nt2*2+kt))<<9)+(l<<3));
        acc=__builtin_amdgcn_mfma_f32_16x16x32_bf16(a2,b,acc,0,0,0);
      }
      g4acc[ii]=acc;
    }
    for(int i=t;i<512;i+=256){
      int r=i>>5, c=(i&31)<<2;
      short4 sv4=*(short4*)&ffh[r][c];
      float x0=s2f(sv4.x), x1=s2f(sv4.y), x2=s2f(sv4.z), x3=s2f(sv4.w);
      sv4.x=f2s(x0*sigm(x0)); sv4.y=f2s(x1*sigm(x1)); sv4.z=f2s(x2*sigm(x2)); sv4.w=f2s(x3*sigm(x3));
      *(short4*)&ffh[r][c]=sv4;
    }
  }
  __syncthreads();

  // ---- P5b: frag-stage silu(f) -> asA ; gates -> g4acc
  {
    short4 sa=*(const short4*)&ffh[fr][(kt4<<5)+(fg<<2)];
    short4 sb=*(const short4*)&ffh[fr][(kt4<<5)+16+(fg<<2)];
    *(short8v*)((char*)asA+(kt4<<10)+(lam<<4))=pack8s(sa,sb);
  }
  {
    #pragma unroll
    for(int ii=0;ii<3;ii++){
      int tid=w*3+ii, nt2=tid&3;
      int uu=(nt2<<4)+(l&15);
      #pragma unroll
      for(int r=0;r<4;r++){
        int row=((l>>4)<<2)+r;
        g4acc[ii][r]*=sigm(s2f(ffh[row][128+uu]));
      }
    }
  }
  __syncthreads();

  // ---- P6b: gv -> ffh[:,0:192]
  {
    #pragma unroll
    for(int ii=0;ii<3;ii++){
      int tid=w*3+ii, p=tid>>2, nt2=tid&3;
      int uu=(nt2<<4)+(l&15);
      #pragma unroll
      for(int r=0;r<4;r++){
        int row=((l>>4)<<2)+r;
        ffh[row][(p<<6)+uu]=f2s(g4acc[ii][r]);
      }
    }
  }
  __syncthreads();
  // ---- P6c: frag-stage gv -> avA
  for(int i=t;i<384;i+=256){
    int seg=i>>6, lm=i&63, r=lm&15, g=lm>>4;
    int p=seg>>1, k2=seg&1;
    short4 sa=*(const short4*)&ffh[r][(p<<6)+(k2<<5)+(g<<2)];
    short4 sb=*(const short4*)&ffh[r][(p<<6)+(k2<<5)+16+(g<<2)];
    *(short8v*)((char*)avA+(seg<<10)+(lm<<4))=pack8s(sa,sb);
  }
  __syncthreads();

  // ---- P7: G5 (silu(f)@W2_s -> xs+=), G6 (gv@W2_v -> xvh+=)
  {
    short8v a[4];
    #pragma unroll
    for(int kt=0;kt<4;kt++) a[kt]=*(const short8v*)((const char*)asA+(kt<<10)+(l<<4));
    #pragma unroll
    for(int ii=0;ii<2;ii++){
      int nt=w+(ii<<2);
      f32x4 acc={0.f,0.f,0.f,0.f};
      #pragma unroll
      for(int kt=0;kt<4;kt++){
        short8v b=*(const short8v*)(P+(((size_t)(T_W2S+nt*4+kt))<<9)+(l<<3));
        acc=__builtin_amdgcn_mfma_f32_16x16x32_bf16(a[kt],b,acc,0,0,0);
      }
      int col=(nt<<4)+(l&15);
      float bv=b2_s[col];
      #pragma unroll
      for(int r=0;r<4;r++){ int row=((l>>4)<<2)+r; xs[row][col]+=acc[r]+bv; }
    }
    #pragma unroll
    for(int ii=0;ii<3;ii++){
      int tid=w*3+ii, p=tid>>2, nt2=tid&3;
      f32x4 acc={0.f,0.f,0.f,0.f};
      #pragma unroll
      for(int kt=0;kt<2;kt++){
        short8v a2=*(const short8v*)((const char*)avA+(((p<<1)+kt)<<10)+(l<<4));
        short8v b=*(const short8v*)(P+(((size_t)(T_W2V+nt2*2+kt))<<9)+(l<<3));
        acc=__builtin_amdgcn_mfma_f32_16x16x32_bf16(a2,b,acc,0,0,0);
      }
      int col=(p<<6)+(nt2<<4)+(l&15);
      #pragma unroll
      for(int r=0;r<4;r++){
        int row=((l>>4)<<2)+r;
        float x=s2f(xvh[row][col]);
        xvh[row][col]=f2s(x+acc[r]);
      }
    }
  }
  __syncthreads();

  // ---- P8: LN2 stats
  {
    const int nn=t>>4, g=t&15;
    float sum=0,sq=0;
    #pragma unroll
    for(int j=0;j<8;j++){ float x=xs[nn][g+16*j]; sum+=x; sq+=x*x; }
    sum=gred16(sum); sq=gred16(sq);
    float mean=sum*(1.f/128.f);
    float var=sq*(1.f/128.f)-mean*mean;
    float vsq=0;
    #pragma unroll
    for(int j=0;j<12;j++){ float x=s2f(xvh[nn][g+16*j]); vsq+=x*x; }
    vsq=gred16(vsq);
    if(g==0){ smean[nn]=mean; srs[nn]=rsqrtf(var+1e-5f); svn[nn]=rsqrtf(vsq*(1.f/64.f)+1e-5f); }
  }
  __syncthreads();

  // ---- P9: store
  for(int i=t;i<16*320;i+=256){
    int nn=i/320, c=i-nn*320;
    float v;
    if(c<128) v=(xs[nn][c]-smean[nn])*srs[nn];
    else { int j=c-128; int u=j/3, k=j-u*3; v=s2f(xvh[nn][(k<<6)+u])*svn[nn]; }
    out[(size_t)(n0+nn)*320+c]=v;
  }
}

// ---------------------------------------------------------------------------
extern "C" void kernel_launch(void* const* d_in, const int* in_sizes, int n_in,
                              void* d_out, int out_size, void* d_ws, size_t ws_size,
                              hipStream_t stream)
{
  (void)in_sizes; (void)n_in; (void)out_size; (void)ws_size;
  const float* nf    =(const float*)d_in[0];
  const float* eattr =(const float*)d_in[1];
  const float* esh   =(const float*)d_in[2];
  const float* Wq    =(const float*)d_in[3];  const float* bq  =(const float*)d_in[4];
  const float* Wk    =(const float*)d_in[5];  const float* bk  =(const float*)d_in[6];
  const float* We    =(const float*)d_in[7];  const float* be  =(const float*)d_in[8];
  const float* Wv_s  =(const float*)d_in[9];  const float* bv_s=(const float*)d_in[10];
  const float* Wv_v  =(const float*)d_in[11];
  const float* w_ss  =(const float*)d_in[12]; const float* w_vv_s=(const float*)d_in[13];
  const float* w_ssg =(const float*)d_in[14]; const float* w_vvg =(const float*)d_in[15];
  const float* b_ms  =(const float*)d_in[16]; const float* b_mg  =(const float*)d_in[17];
  const float* w_sv  =(const float*)d_in[18]; const float* w_vs  =(const float*)d_in[19];
  const float* w_vvv =(const float*)d_in[20];
  const float* Wo_s  =(const float*)d_in[21]; const float* bo_s  =(const float*)d_in[22];
  const float* Wo_v  =(const float*)d_in[23];
  const float* W1_s  =(const float*)d_in[24]; const float* b1_s  =(const float*)d_in[25];
  const float* W1_v  =(const float*)d_in[26];
  const float* W2_s  =(const float*)d_in[27]; const float* b2_s  =(const float*)d_in[28];
  const float* W2_v  =(const float*)d_in[29];
  const int*   eidx  =(const int*)d_in[30];
  float* out=(float*)d_out;

  char* w=(char*)d_ws;
  bf16* Q    =(bf16*)w;  w+=(size_t)NNODE*256*2;
  bf16* Kb   =(bf16*)w;  w+=(size_t)NNODE*256*2;
  short* NREC2=(short*)w; w+=(size_t)NNODE*1280*2;
  float* SC  =(float*)w; w+=(size_t)NEDGE*16*4;
  float* ESHs=(float*)w; w+=(size_t)NEDGE*4*4;
  float* ATTs=(float*)w; w+=(size_t)NEDGE*4;
  short* AGSh=(short*)w; w+=(size_t)NNODE*128*2;
  short* AGVh=(short*)w; w+=(size_t)NNODE*192*2;
  short* P   =(short*)w; w+=(size_t)T_TOT*512*2;
  int* COUNTS=(int*)w;   w+=(size_t)NNODE*4;
  int* OFFb  =(int*)w;   w+=(size_t)(NNODE+1)*4;
  int* CURSOR=(int*)w;   w+=(size_t)NNODE*4;
  int* EORDb =(int*)w;   w+=(size_t)NEDGE*4;
  int* SRCs  =(int*)w;   w+=(size_t)NEDGE*4;
  int* BSUM  =(int*)w;   w+=(size_t)256*4;
  int* BOFF  =(int*)w;   w+=(size_t)256*4;
  // DSTs aliases ATTs: written by k_scatter, read by k3; ATTs written later
  // by k5. Same-stream ordering; keeps ws under the 256MiB budget.
  int* DSTs = (int*)ATTs;

  hipMemsetAsync(COUNTS,0,(size_t)NNODE*4,stream);

  k_prep    <<<T_TOT,64,0,stream>>>(Wo_s,Wo_v,W1_s,W1_v,W2_s,W2_v,We,
                                    Wq,Wk,Wv_s,w_ss,w_ssg,w_sv,
                                    Wv_v,w_vv_s,w_vvg,w_vs,w_vvv,P);
  k_hist    <<<(NEDGE+255)/256,256,0,stream>>>(eidx,COUNTS);
  k_scan1   <<<SCAN_NB,256,0,stream>>>(COUNTS,BSUM);
  k_scan2   <<<1,256,0,stream>>>(BSUM,BOFF);
  k_scan3   <<<SCAN_NB,256,0,stream>>>(COUNTS,BOFF,OFFb,CURSOR);
  k_scatter <<<(NEDGE+255)/256,256,0,stream>>>(eidx,esh,CURSOR,EORDb,SRCs,DSTs,ESHs);
  k1_mfma   <<<NNODE/16,256,0,stream>>>(nf,P,bq,bk,bv_s,Q,Kb,NREC2);
  k2_mfma   <<<NNODE/16,256,0,stream>>>(nf,P,NREC2);
  k3_mfma   <<<NEDGE/16,256,0,stream>>>(eattr,EORDb,SRCs,DSTs,P,be,Q,Kb,SC);
  k5_att    <<<NNODE/4,256,0,stream>>>(SC,OFFb,ATTs);
  k6_agg    <<<NNODE/4,256,0,stream>>>(SRCs,ESHs,NREC2,ATTs,OFFb,b_ms,b_mg,AGSh,AGVh);
  k7_mfma   <<<NNODE/16,256,0,stream>>>(nf,AGSh,AGVh,P,bo_s,b1_s,b2_s,out);
}